// Round 3
// baseline (998.506 us; speedup 1.0000x reference)
//
#include <hip/hip_runtime.h>

// GRUFeatureExtractor: 2-layer GRU (B=4096, T=256, D_IN=128, H=64) + FC -> [B,1]
// Single fused persistent kernel: streams x once, never materializes gx0/h1_seq/h2_seq.
//
// R2/R3: LAYER-SPLIT WAVE PIPELINE. R1's counters showed Occupancy=11.6% (1 wave/SIMD,
// grid-limited) with ~4300 cyc/step vs ~800 cyc of issue work -> latency-bound with
// zero TLP. Now: 256 blocks x 512 threads (8 waves = 2/SIMD). Waves 0-3 (L0) compute
// h1[t] while waves 4-7 (L1) compute h2[t-1] from the h1 LDS double-buffer.
// Per-wave critical path per phase is ~halved AND each SIMD gets one L0 + one L1
// wave to overlap stalls. One lgkmcnt-only barrier per phase (vmcnt never drained:
// x prefetch stays in flight, T4 discipline).
// (R3 = byte-identical resubmission of R2: the R2 bench was an infra failure —
// container push took 53 min in R1; no counter evidence was produced.)
//
// Layout per block: 16 batch rows; within a group, wave owns 16 h-cols
// (r/z/n N-tiles {16w, 64+16w, 128+16w}). f16 MFMA operands (2^-11 rel err ->
// recurrence err ~1e-4 << threshold), fp32 accum, fp32 biases as accumulator init.
// Weights live in VGPRs for the whole T-loop; wA/wB are path-shared unions
// (L0: Wih0[3][4]+Whh0[3][2]; L1: Wih1[3][2]+Whh1[3][2]) to fit 2 waves/SIMD.

#define TT  256
#define DIN 128
#define HH  64

typedef _Float16 f16x8 __attribute__((ext_vector_type(8)));
typedef float    f32x4 __attribute__((ext_vector_type(4)));

__device__ __forceinline__ float fast_sigmoid(float x) {
    float e = __builtin_amdgcn_exp2f(-1.44269504088896f * x);
    return __builtin_amdgcn_rcpf(1.0f + e);
}
__device__ __forceinline__ float fast_tanh(float x) {
    // tanh(x) = 1 - 2/(exp2(2*log2e*x)+1); saturates correctly at +-inf
    float e = __builtin_amdgcn_exp2f(2.88539008177793f * x);
    return 1.0f - 2.0f * __builtin_amdgcn_rcpf(1.0f + e);
}

// LDS-only barrier: waits this wave's outstanding DS ops (producer-side write
// visibility), then raw s_barrier. Does NOT drain vmcnt -> global prefetch loads
// stay in flight across phases. Memory-clobber asm pins DS ops to their side.
__device__ __forceinline__ void lds_barrier() {
    asm volatile("s_waitcnt lgkmcnt(0)" ::: "memory");
    __builtin_amdgcn_s_barrier();
    asm volatile("" ::: "memory");
}

__global__ __launch_bounds__(512, 2) void gru_fused_kernel(
    const float* __restrict__ x,
    const float* __restrict__ Wih0, const float* __restrict__ Whh0,
    const float* __restrict__ bih0, const float* __restrict__ bhh0,
    const float* __restrict__ Wih1, const float* __restrict__ Whh1,
    const float* __restrict__ bih1, const float* __restrict__ bhh1,
    const float* __restrict__ Wfc,  const float* __restrict__ bfc,
    float* __restrict__ out)
{
    const int tid  = threadIdx.x;
    const int wv   = tid >> 6;        // wave 0..7
    const int lane = tid & 63;
    const int q    = lane >> 4;       // quad 0..3
    const int lm   = lane & 15;
    const bool isL0 = (wv < 4);       // waves 0-3: layer 0; waves 4-7: layer 1
    const int cw   = (wv & 3) << 4;   // this wave's h-col base within its layer
    const int b0   = blockIdx.x << 4;

    // stride HH+8=72 f16 (144 B): A-frag b128 reads spread bank groups
    __shared__ __align__(16) _Float16 h1buf[2][16][HH + 8];
    __shared__ __align__(16) _Float16 h2buf[2][16][HH + 8];
    __shared__ float ored[4][16];

    // ---- x prefetch (L0 waves only; issue first: longest latency) ----
    // A-frag: lane provides A[m=lm][k=q*8+j] per 32-wide kstep s.
    const float* xrow = x + (size_t)(b0 + lm) * TT * DIN + q * 8;
    float4 xa0[8], xa1[8];
    auto prefetch = [&](int t, float4 (&xb)[8]) {
        const float* p = xrow + t * DIN;
        #pragma unroll
        for (int s = 0; s < 4; s++) {
            xb[2 * s]     = *(const float4*)(p + s * 32);
            xb[2 * s + 1] = *(const float4*)(p + s * 32 + 4);
        }
    };
    if (isL0) { prefetch(0, xa0); prefetch(1, xa1); }

    // ---- weight fragments into registers (B-layout: lane = B[k=q*8+j][n=lm]) ----
    // W stored [N=3H][K] row-major, so B-frag = 8 consecutive floats of row n.
    // Path-shared union: L0 -> wA=Wih0 (4 ksteps), wB=Whh0; L1 -> wA[0..1]=Wih1, wB=Whh1.
    f16x8 wA[3][4], wB[3][2];
    float bx[3], bh[3];
    #pragma unroll
    for (int g = 0; g < 3; g++) {
        const int n = g * 64 + cw + lm;
        if (isL0) {
            #pragma unroll
            for (int s = 0; s < 4; s++) {
                const float* p = Wih0 + n * DIN + s * 32 + q * 8;
                #pragma unroll
                for (int j = 0; j < 8; j++) wA[g][s][j] = (_Float16)p[j];
            }
            #pragma unroll
            for (int s = 0; s < 2; s++) {
                const float* p = Whh0 + n * HH + s * 32 + q * 8;
                #pragma unroll
                for (int j = 0; j < 8; j++) wB[g][s][j] = (_Float16)p[j];
            }
            bx[g] = bih0[n]; bh[g] = bhh0[n];
        } else {
            #pragma unroll
            for (int s = 0; s < 2; s++) {
                const float* pa = Wih1 + n * HH + s * 32 + q * 8;
                const float* pb = Whh1 + n * HH + s * 32 + q * 8;
                #pragma unroll
                for (int j = 0; j < 8; j++) {
                    wA[g][s][j] = (_Float16)pa[j];
                    wB[g][s][j] = (_Float16)pb[j];
                }
            }
            bx[g] = bih1[n]; bh[g] = bhh1[n];
        }
    }

    // ---- zero h state (h0 = 0 for both layers, both parity buffers) ----
    {
        _Float16* z1 = &h1buf[0][0][0];
        _Float16* z2 = &h2buf[0][0][0];
        const int total = 2 * 16 * (HH + 8);
        for (int i = tid; i < total; i += 512) { z1[i] = (_Float16)0; z2[i] = (_Float16)0; }
    }
    float hC[4] = {0.f, 0.f, 0.f, 0.f};   // C-layout state: L0 holds h1, L1 holds h2
    __syncthreads();

    // ---- L0 phase body: compute h1[t] ----
    // reads h1buf[t&1] (h1[t-1] A-layout), writes h1buf[1-(t&1)] (h1[t] C-layout)
    auto L0step = [&](int t, float4 (&xb)[8]) {
        const int p = t & 1;
        f16x8 ax[4];
        #pragma unroll
        for (int s = 0; s < 4; s++) {
            const float4 u = xb[2 * s], v = xb[2 * s + 1];
            ax[s][0] = (_Float16)u.x; ax[s][1] = (_Float16)u.y;
            ax[s][2] = (_Float16)u.z; ax[s][3] = (_Float16)u.w;
            ax[s][4] = (_Float16)v.x; ax[s][5] = (_Float16)v.y;
            ax[s][6] = (_Float16)v.z; ax[s][7] = (_Float16)v.w;
        }
        if (t + 2 < TT) prefetch(t + 2, xb);   // distance-2 prefetch, same buffer

        f16x8 ah[2];
        ah[0] = *(const f16x8*)&h1buf[p][lm][q * 8];
        ah[1] = *(const f16x8*)&h1buf[p][lm][32 + q * 8];

        f32x4 agx[3], agh[3];
        #pragma unroll
        for (int g = 0; g < 3; g++) agx[g] = (f32x4){bx[g], bx[g], bx[g], bx[g]};
        #pragma unroll
        for (int s = 0; s < 4; s++)
            #pragma unroll
            for (int g = 0; g < 3; g++)
                agx[g] = __builtin_amdgcn_mfma_f32_16x16x32_f16(ax[s], wA[g][s], agx[g], 0, 0, 0);
        #pragma unroll
        for (int g = 0; g < 3; g++) agh[g] = (f32x4){bh[g], bh[g], bh[g], bh[g]};
        #pragma unroll
        for (int s = 0; s < 2; s++)
            #pragma unroll
            for (int g = 0; g < 3; g++)
                agh[g] = __builtin_amdgcn_mfma_f32_16x16x32_f16(ah[s], wB[g][s], agh[g], 0, 0, 0);

        // gates (PyTorch order r,z,n; b_hh_n stays inside r*gh_n)
        #pragma unroll
        for (int r = 0; r < 4; r++) {
            const float rr = fast_sigmoid(agx[0][r] + agh[0][r]);
            const float zz = fast_sigmoid(agx[1][r] + agh[1][r]);
            const float nn = fast_tanh(agx[2][r] + rr * agh[2][r]);
            hC[r] = nn + zz * (hC[r] - nn);
            h1buf[1 - p][q * 4 + r][cw + lm] = (_Float16)hC[r];
        }
    };

    // ---- L1 phase body: compute h2[t] ----
    // reads h1buf[(t+1)&1] (h1[t] A-layout, written by L0 last phase),
    //       h2buf[t&1]     (h2[t-1] A-layout),
    // writes h2buf[(t+1)&1] (h2[t] C-layout)
    auto L1step = [&](int t) {
        const int w = (t + 1) & 1;
        f16x8 ahx[2], ahh[2];
        ahx[0] = *(const f16x8*)&h1buf[w][lm][q * 8];
        ahx[1] = *(const f16x8*)&h1buf[w][lm][32 + q * 8];
        ahh[0] = *(const f16x8*)&h2buf[1 - w][lm][q * 8];
        ahh[1] = *(const f16x8*)&h2buf[1 - w][lm][32 + q * 8];

        f32x4 agx[3], agh[3];
        #pragma unroll
        for (int g = 0; g < 3; g++) {
            agx[g] = (f32x4){bx[g], bx[g], bx[g], bx[g]};
            agh[g] = (f32x4){bh[g], bh[g], bh[g], bh[g]};
        }
        #pragma unroll
        for (int s = 0; s < 2; s++)
            #pragma unroll
            for (int g = 0; g < 3; g++) {
                agx[g] = __builtin_amdgcn_mfma_f32_16x16x32_f16(ahx[s], wA[g][s], agx[g], 0, 0, 0);
                agh[g] = __builtin_amdgcn_mfma_f32_16x16x32_f16(ahh[s], wB[g][s], agh[g], 0, 0, 0);
            }
        #pragma unroll
        for (int r = 0; r < 4; r++) {
            const float rr = fast_sigmoid(agx[0][r] + agh[0][r]);
            const float zz = fast_sigmoid(agx[1][r] + agh[1][r]);
            const float nn = fast_tanh(agx[2][r] + rr * agh[2][r]);
            hC[r] = nn + zz * (hC[r] - nn);
            h2buf[w][q * 4 + r][cw + lm] = (_Float16)hC[r];
        }
    };

    // ---- pipelined phase loop: phase k runs L0(h1[k]) || L1(h2[k-1]) ----
    for (int k = 0; k < TT; k += 2) {   // unroll x2 so xa0/xa1 indices are compile-time
        if (isL0)       L0step(k, xa0);
        else if (k > 0) L1step(k - 1);
        lds_barrier();
        if (isL0) L0step(k + 1, xa1);
        else      L1step(k);
        lds_barrier();
    }
    // drain phase: h2[TT-1] (L1 only; h1[TT-1] already in h1buf from phase TT-1)
    if (!isL0) L1step(TT - 1);

    // ---- out[b] = h2_last[b,:] . Wfc + bfc (L1 waves hold h2C) ----
    if (!isL0) {
        const float wf = Wfc[cw + lm];
        float pr[4];
        #pragma unroll
        for (int r = 0; r < 4; r++) pr[r] = hC[r] * wf;
        #pragma unroll
        for (int m = 1; m < 16; m <<= 1) {
            #pragma unroll
            for (int r = 0; r < 4; r++) pr[r] += __shfl_xor(pr[r], m, 64);
        }
        if (lm == 0) {
            #pragma unroll
            for (int r = 0; r < 4; r++) ored[wv - 4][q * 4 + r] = pr[r];
        }
    }
    __syncthreads();
    if (tid < 16) {
        out[b0 + tid] = ored[0][tid] + ored[1][tid] + ored[2][tid] + ored[3][tid] + bfc[0];
    }
}

extern "C" void kernel_launch(void* const* d_in, const int* in_sizes, int n_in,
                              void* d_out, int out_size, void* d_ws, size_t ws_size,
                              hipStream_t stream) {
    (void)in_sizes; (void)n_in; (void)d_ws; (void)ws_size; (void)out_size;
    const float* x    = (const float*)d_in[0];
    const float* Wih0 = (const float*)d_in[1];
    const float* Whh0 = (const float*)d_in[2];
    const float* bih0 = (const float*)d_in[3];
    const float* bhh0 = (const float*)d_in[4];
    const float* Wih1 = (const float*)d_in[5];
    const float* Whh1 = (const float*)d_in[6];
    const float* bih1 = (const float*)d_in[7];
    const float* bhh1 = (const float*)d_in[8];
    const float* Wfc  = (const float*)d_in[9];
    const float* bfc  = (const float*)d_in[10];
    float* out = (float*)d_out;

    gru_fused_kernel<<<dim3(4096 / 16), dim3(512), 0, stream>>>(
        x, Wih0, Whh0, bih0, bhh0, Wih1, Whh1, bih1, bhh1, Wfc, bfc, out);
}